// Round 5
// baseline (106.810 us; speedup 1.0000x reference)
//
#include <hip/hip_runtime.h>
#include <math.h>

typedef __attribute__((ext_vector_type(8))) short bf16x8;
typedef __attribute__((ext_vector_type(4))) float f32x4;

#define WSTR  68     // G-buffer row stride in shorts (136B): conflict-free frag reads
#define ITERS 8      // 16 batches per block-iter -> 128 batches per block

__device__ __forceinline__ unsigned short f2b(float f) {   // fp32 -> bf16 RNE
    union { float f; unsigned int u; } x; x.f = f;
    unsigned int r = x.u + 0x7FFFu + ((x.u >> 16) & 1u);
    return (unsigned short)(r >> 16);
}

// gelu(x) = x*sigmoid(2y), y = 0.7978845608*x*(1+0.044715*x^2)   (tanh-form, hw exp2)
__device__ __forceinline__ float gelu_t(float x) {
    float x2 = x * x;
    float z  = x * fmaf(0.10294324f, x2, 2.3022082f);
    float e  = __builtin_amdgcn_exp2f(z);
    float r  = __builtin_amdgcn_rcpf(1.0f + e);
    return fmaf(x, -r, x);          // x*(1-r)
}

// prep: w1t[n*64+k] = W1cat[k][n]  (n<64: W1top col n, n>=64: W1bot col n-64)
//       w2t[n*64+k] = W2[k][n];  attn = softmax(edge_attn) rows
__global__ void prep_k(const float* __restrict__ W1, const float* __restrict__ W2,
                       const float* __restrict__ ea, unsigned short* __restrict__ w1t,
                       unsigned short* __restrict__ w2t, float* __restrict__ attn)
{
    int gid = blockIdx.x * 256 + threadIdx.x;
    if (gid < 128 * 64) {
        int n = gid >> 6, k = gid & 63;
        float v = (n < 64) ? W1[k * 64 + n] : W1[(64 + k) * 64 + (n - 64)];
        w1t[gid] = f2b(v);
    } else if (gid < 12288) {
        int idx = gid - 8192;
        int n = idx >> 6, k = idx & 63;
        w2t[idx] = f2b(W2[k * 64 + n]);
    }
    if (gid < 9) {
        int i = gid / 3, j = gid % 3;
        float e0 = ea[i*3+0], e1 = ea[i*3+1], e2 = ea[i*3+2];
        float mx = fmaxf(e0, fmaxf(e1, e2));
        float d = expf(e0-mx) + expf(e1-mx) + expf(e2-mx);
        attn[gid] = expf(ea[i*3+j] - mx) / d;
    }
}

__global__ __launch_bounds__(256, 3)
void edge_mfma4(const float* __restrict__ nodes,
                const unsigned short* __restrict__ w1t,
                const unsigned short* __restrict__ w2t,
                const float* __restrict__ attn9,
                const float* __restrict__ b1,
                const float* __restrict__ b2,
                float* __restrict__ out)
{
    __shared__ __align__(16) unsigned short Gs[4 * 16 * WSTR];   // 8704 B

    const int t = threadIdx.x;
    const int lane = t & 63, wave = t >> 6;
    const int q = lane >> 4, r16 = lane & 15;
    unsigned short* Gw = Gs + wave * 16 * WSTR;                  // wave-private

    // padded tile row r16 -> batch-in-group bA, node-row iA (iA==3 is the dummy row)
    const int bA = r16 >> 2;
    const int iA = r16 & 3;
    const int iAr = (iA == 3) ? 0 : iA;

    // ---- weight fragments: load ONCE, runtime loop keeps them resident ----
    bf16x8 w1f[8][2], w2f[4][2];
    #pragma unroll
    for (int nt = 0; nt < 8; ++nt)
        #pragma unroll
        for (int ks = 0; ks < 2; ++ks)
            w1f[nt][ks] = *(const bf16x8*)&w1t[(nt*16 + r16) * 64 + ks*32 + q*8];
    #pragma unroll
    for (int nt = 0; nt < 4; ++nt)
        #pragma unroll
        for (int ks = 0; ks < 2; ++ks)
            w2f[nt][ks] = *(const bf16x8*)&w2t[(nt*16 + r16) * 64 + ks*32 + q*8];

    // attn weights pinned to SGPRs (wave-uniform)
    float aw[9];
    #pragma unroll
    for (int i = 0; i < 9; ++i) {
        union { float f; int u; } c; c.f = attn9[i];
        c.u = __builtin_amdgcn_readfirstlane(c.u);
        aw[i] = c.f;
    }
    float b1c[4];
    #pragma unroll
    for (int nt = 0; nt < 4; ++nt) b1c[nt] = b1[nt*16 + r16];

    // per-lane streaming pointers (advance 16 batches = 3072 floats per iter)
    const long batch0 = (long)blockIdx.x * (ITERS * 16) + wave * 4 + bA;
    const float* xlane = nodes + (batch0 * 3 + iAr) * 64 + q * 8;
    float*       olane = out   + (batch0 * 3 + iA ) * 64 + q * 4;

    // prime iter-0 X
    f32x4 c0 = *(const f32x4*)(xlane);
    f32x4 c1 = *(const f32x4*)(xlane + 4);
    f32x4 c2 = *(const f32x4*)(xlane + 32);
    f32x4 c3 = *(const f32x4*)(xlane + 36);

    for (int it = 0; it < ITERS; ++it) {
        // ---- prefetch next iteration's X (clamped on last iter) ----
        const float* xn = xlane + (long)((it + 1 < ITERS) ? it + 1 : it) * 3072;
        f32x4 n0 = *(const f32x4*)(xn);
        f32x4 n1 = *(const f32x4*)(xn + 4);
        f32x4 n2 = *(const f32x4*)(xn + 32);
        f32x4 n3 = *(const f32x4*)(xn + 36);

        // ---- current X -> A-frags (k = ks*32 + q*8 + e) ----
        bf16x8 afr0, afr1;
        #pragma unroll
        for (int e = 0; e < 4; ++e) {
            afr0[e]   = (short)f2b(c0[e]); afr0[4+e] = (short)f2b(c1[e]);
            afr1[e]   = (short)f2b(c2[e]); afr1[4+e] = (short)f2b(c3[e]);
        }

        // ---- GEMM1 + lane-local gelu mix ----
        #pragma unroll
        for (int nt = 0; nt < 4; ++nt) {
            f32x4 z = {0.f, 0.f, 0.f, 0.f};
            z = __builtin_amdgcn_mfma_f32_16x16x32_bf16(afr0, w1f[nt][0], z, 0, 0, 0);
            z = __builtin_amdgcn_mfma_f32_16x16x32_bf16(afr1, w1f[nt][1], z, 0, 0, 0);
            f32x4 y = {0.f, 0.f, 0.f, 0.f};
            y = __builtin_amdgcn_mfma_f32_16x16x32_bf16(afr0, w1f[nt+4][0], y, 0, 0, 0);
            y = __builtin_amdgcn_mfma_f32_16x16x32_bf16(afr1, w1f[nt+4][1], y, 0, 0, 0);

            float u0 = z[0] + b1c[nt], u1 = z[1] + b1c[nt], u2 = z[2] + b1c[nt];
            float gg0 = 0.f, gg1 = 0.f, gg2 = 0.f;
            #pragma unroll
            for (int j = 0; j < 3; ++j) {
                float vj = y[j];
                float gl0 = gelu_t(u0 + vj);
                float gl1 = gelu_t(u1 + vj);
                float gl2 = gelu_t(u2 + vj);
                gg0 = fmaf(aw[0*3+j], gl0, gg0);
                gg1 = fmaf(aw[1*3+j], gl1, gg1);
                gg2 = fmaf(aw[2*3+j], gl2, gg2);
            }
            Gw[(q*4 + 0) * WSTR + nt*16 + r16] = f2b(gg0);
            Gw[(q*4 + 1) * WSTR + nt*16 + r16] = f2b(gg1);
            Gw[(q*4 + 2) * WSTR + nt*16 + r16] = f2b(gg2);
        }
        // same-wave DS ordering: compiler emits lgkmcnt before dependent reads

        // ---- GEMM2 (operand-swapped): C[row=msg_col][col=msg_row] ----
        bf16x8 gfr0 = *(const bf16x8*)&Gw[r16 * WSTR + q*8];
        bf16x8 gfr1 = *(const bf16x8*)&Gw[r16 * WSTR + 32 + q*8];
        #pragma unroll
        for (int nt = 0; nt < 4; ++nt) {
            f32x4 acc = {0.f, 0.f, 0.f, 0.f};
            acc = __builtin_amdgcn_mfma_f32_16x16x32_bf16(w2f[nt][0], gfr0, acc, 0, 0, 0);
            acc = __builtin_amdgcn_mfma_f32_16x16x32_bf16(w2f[nt][1], gfr1, acc, 0, 0, 0);
            if (iA != 3) {
                f32x4 b2v = *(const f32x4*)(b2 + nt*16 + q*4);   // L1-hot, reloaded per use
                f32x4 o = acc + b2v;
                __builtin_nontemporal_store(o, (f32x4*)(olane + (long)it * 3072 + nt * 16));
            }
        }

        c0 = n0; c1 = n1; c2 = n2; c3 = n3;
        xlane += 0;  // offsets handled via it*3072 on xn; keep base fixed
    }
}

extern "C" void kernel_launch(void* const* d_in, const int* in_sizes, int n_in,
                              void* d_out, int out_size, void* d_ws, size_t ws_size,
                              hipStream_t stream)
{
    const float* nodes = (const float*)d_in[0];
    const float* W1    = (const float*)d_in[1];
    const float* b1    = (const float*)d_in[2];
    const float* W2    = (const float*)d_in[3];
    const float* b2    = (const float*)d_in[4];
    const float* ea    = (const float*)d_in[5];
    float* out = (float*)d_out;

    unsigned short* w1t = (unsigned short*)d_ws;          // 8192 shorts
    unsigned short* w2t = w1t + 8192;                     // 4096 shorts
    float* attn = (float*)(w2t + 4096);                   // 9 floats

    prep_k<<<48, 256, 0, stream>>>(W1, W2, ea, w1t, w2t, attn);

    const int batches = (out_size / 64) / 3;              // 262144
    const int blocks = batches / (ITERS * 16);            // 2048
    edge_mfma4<<<blocks, 256, 0, stream>>>(nodes, w1t, w2t, attn, b1, b2, out);
}

// Round 6
// 104.986 us; speedup vs baseline: 1.0174x; 1.0174x over previous
//
#include <hip/hip_runtime.h>
#include <hip/hip_bf16.h>
#include <math.h>

typedef __attribute__((ext_vector_type(8))) short bf16x8;
typedef __attribute__((ext_vector_type(4))) float f32x4;

#define WSTR  68     // G-buffer row stride in shorts (136B): conflict-free frag reads
#define ITERS 8      // 16 batches per block-iter -> 128 batches per block

#define PIN(x) asm volatile("" : "+v"(x))   // force value resident in VGPRs across loop

__device__ __forceinline__ short f2bs(float f) {   // fp32 -> bf16 RNE via hw cvt
    union { __hip_bfloat16 b; short s; } u;
    u.b = __float2bfloat16(f);
    return u.s;
}

__device__ __forceinline__ unsigned short f2b_int(float f) {  // prep-kernel path (cold)
    union { float f; unsigned int u; } x; x.f = f;
    unsigned int r = x.u + 0x7FFFu + ((x.u >> 16) & 1u);
    return (unsigned short)(r >> 16);
}

// gelu(x) = x*sigmoid(2y), y = 0.7978845608*x*(1+0.044715*x^2)   (tanh-form, hw exp2)
__device__ __forceinline__ float gelu_t(float x) {
    float x2 = x * x;
    float z  = x * fmaf(0.10294324f, x2, 2.3022082f);
    float e  = __builtin_amdgcn_exp2f(z);
    float r  = __builtin_amdgcn_rcpf(1.0f + e);
    return fmaf(x, -r, x);          // x*(1-r)
}

// prep: w1t[n*64+k] = W1cat[k][n]  (n<64: W1top col n, n>=64: W1bot col n-64)
//       w2t[n*64+k] = W2[k][n];  attn = softmax(edge_attn) rows
__global__ void prep_k(const float* __restrict__ W1, const float* __restrict__ W2,
                       const float* __restrict__ ea, unsigned short* __restrict__ w1t,
                       unsigned short* __restrict__ w2t, float* __restrict__ attn)
{
    int gid = blockIdx.x * 256 + threadIdx.x;
    if (gid < 128 * 64) {
        int n = gid >> 6, k = gid & 63;
        float v = (n < 64) ? W1[k * 64 + n] : W1[(64 + k) * 64 + (n - 64)];
        w1t[gid] = f2b_int(v);
    } else if (gid < 12288) {
        int idx = gid - 8192;
        int n = idx >> 6, k = idx & 63;
        w2t[idx] = f2b_int(W2[k * 64 + n]);
    }
    if (gid < 9) {
        int i = gid / 3, j = gid % 3;
        float e0 = ea[i*3+0], e1 = ea[i*3+1], e2 = ea[i*3+2];
        float mx = fmaxf(e0, fmaxf(e1, e2));
        float d = expf(e0-mx) + expf(e1-mx) + expf(e2-mx);
        attn[gid] = expf(ea[i*3+j] - mx) / d;
    }
}

__global__ __launch_bounds__(256, 3)
void edge_mfma5(const float* __restrict__ nodes,
                const unsigned short* __restrict__ w1t,
                const unsigned short* __restrict__ w2t,
                const float* __restrict__ attn9,
                const float* __restrict__ b1,
                const float* __restrict__ b2,
                float* __restrict__ out)
{
    __shared__ __align__(16) unsigned short Gs[4 * 16 * WSTR];   // 8704 B

    const int t = threadIdx.x;
    const int lane = t & 63, wave = t >> 6;
    const int q = lane >> 4, r16 = lane & 15;
    unsigned short* Gw = Gs + wave * 16 * WSTR;                  // wave-private

    // padded tile row r16 -> batch-in-group bA, node-row iA (iA==3 is the dummy row)
    const int bA = r16 >> 2;
    const int iA = r16 & 3;
    const int iAr = (iA == 3) ? 0 : iA;

    // ---- weight fragments: load ONCE, then PIN so they stay in VGPRs ----
    bf16x8 w1f[8][2], w2f[4][2];
    #pragma unroll
    for (int nt = 0; nt < 8; ++nt)
        #pragma unroll
        for (int ks = 0; ks < 2; ++ks)
            w1f[nt][ks] = *(const bf16x8*)&w1t[(nt*16 + r16) * 64 + ks*32 + q*8];
    #pragma unroll
    for (int nt = 0; nt < 4; ++nt)
        #pragma unroll
        for (int ks = 0; ks < 2; ++ks)
            w2f[nt][ks] = *(const bf16x8*)&w2t[(nt*16 + r16) * 64 + ks*32 + q*8];
    #pragma unroll
    for (int nt = 0; nt < 8; ++nt) { PIN(w1f[nt][0]); PIN(w1f[nt][1]); }
    #pragma unroll
    for (int nt = 0; nt < 4; ++nt) { PIN(w2f[nt][0]); PIN(w2f[nt][1]); }

    // attn weights pinned to SGPRs (wave-uniform)
    float aw[9];
    #pragma unroll
    for (int i = 0; i < 9; ++i) {
        union { float f; int u; } c; c.f = attn9[i];
        c.u = __builtin_amdgcn_readfirstlane(c.u);
        aw[i] = c.f;
    }
    float b1c[4];
    #pragma unroll
    for (int nt = 0; nt < 4; ++nt) b1c[nt] = b1[nt*16 + r16];

    // per-lane streaming pointers (advance 16 batches = 3072 floats per iter)
    const long batch0 = (long)blockIdx.x * (ITERS * 16) + wave * 4 + bA;
    const float* xlane = nodes + (batch0 * 3 + iAr) * 64 + q * 8;
    float*       olane = out   + (batch0 * 3 + iA ) * 64 + q * 4;

    // prime iter-0 X and convert to A-frags (k = ks*32 + q*8 + e)
    bf16x8 afr0, afr1;
    {
        f32x4 p0 = *(const f32x4*)(xlane);
        f32x4 p1 = *(const f32x4*)(xlane + 4);
        f32x4 p2 = *(const f32x4*)(xlane + 32);
        f32x4 p3 = *(const f32x4*)(xlane + 36);
        #pragma unroll
        for (int e = 0; e < 4; ++e) {
            afr0[e]   = f2bs(p0[e]); afr0[4+e] = f2bs(p1[e]);
            afr1[e]   = f2bs(p2[e]); afr1[4+e] = f2bs(p3[e]);
        }
    }

    for (int it = 0; it < ITERS; ++it) {
        // ---- prefetch next iteration's X (clamped on last iter) ----
        const float* xn = xlane + (long)((it + 1 < ITERS) ? it + 1 : it) * 3072;
        f32x4 n0 = *(const f32x4*)(xn);
        f32x4 n1 = *(const f32x4*)(xn + 4);
        f32x4 n2 = *(const f32x4*)(xn + 32);
        f32x4 n3 = *(const f32x4*)(xn + 36);

        // ---- GEMM1 + lane-local gelu mix ----
        #pragma unroll
        for (int nt = 0; nt < 4; ++nt) {
            f32x4 z = {0.f, 0.f, 0.f, 0.f};
            z = __builtin_amdgcn_mfma_f32_16x16x32_bf16(afr0, w1f[nt][0], z, 0, 0, 0);
            z = __builtin_amdgcn_mfma_f32_16x16x32_bf16(afr1, w1f[nt][1], z, 0, 0, 0);
            f32x4 y = {0.f, 0.f, 0.f, 0.f};
            y = __builtin_amdgcn_mfma_f32_16x16x32_bf16(afr0, w1f[nt+4][0], y, 0, 0, 0);
            y = __builtin_amdgcn_mfma_f32_16x16x32_bf16(afr1, w1f[nt+4][1], y, 0, 0, 0);

            // lane holds batch q: u rows z[0..2], v rows y[0..2], col nt*16+r16
            float u0 = z[0] + b1c[nt], u1 = z[1] + b1c[nt], u2 = z[2] + b1c[nt];
            float gg0 = 0.f, gg1 = 0.f, gg2 = 0.f;
            #pragma unroll
            for (int j = 0; j < 3; ++j) {
                float vj = y[j];
                float gl0 = gelu_t(u0 + vj);
                float gl1 = gelu_t(u1 + vj);
                float gl2 = gelu_t(u2 + vj);
                gg0 = fmaf(aw[0*3+j], gl0, gg0);
                gg1 = fmaf(aw[1*3+j], gl1, gg1);
                gg2 = fmaf(aw[2*3+j], gl2, gg2);
            }
            Gw[(q*4 + 0) * WSTR + nt*16 + r16] = (unsigned short)f2bs(gg0);
            Gw[(q*4 + 1) * WSTR + nt*16 + r16] = (unsigned short)f2bs(gg1);
            Gw[(q*4 + 2) * WSTR + nt*16 + r16] = (unsigned short)f2bs(gg2);
        }
        // same-wave DS ordering: compiler emits lgkmcnt before dependent reads

        // ---- GEMM2 (operand-swapped): C[row=msg_col][col=msg_row] ----
        bf16x8 gfr0 = *(const bf16x8*)&Gw[r16 * WSTR + q*8];
        bf16x8 gfr1 = *(const bf16x8*)&Gw[r16 * WSTR + 32 + q*8];
        #pragma unroll
        for (int nt = 0; nt < 4; ++nt) {
            f32x4 acc = {0.f, 0.f, 0.f, 0.f};
            acc = __builtin_amdgcn_mfma_f32_16x16x32_bf16(w2f[nt][0], gfr0, acc, 0, 0, 0);
            acc = __builtin_amdgcn_mfma_f32_16x16x32_bf16(w2f[nt][1], gfr1, acc, 0, 0, 0);
            if (iA != 3) {
                f32x4 b2v = *(const f32x4*)(b2 + nt*16 + q*4);   // L1-hot, loop-invariant
                f32x4 o = acc + b2v;
                __builtin_nontemporal_store(o, (f32x4*)(olane + (long)it * 3072 + nt * 16));
            }
        }

        // ---- convert prefetched X for next iteration ----
        #pragma unroll
        for (int e = 0; e < 4; ++e) {
            afr0[e]   = f2bs(n0[e]); afr0[4+e] = f2bs(n1[e]);
            afr1[e]   = f2bs(n2[e]); afr1[4+e] = f2bs(n3[e]);
        }
    }
}

extern "C" void kernel_launch(void* const* d_in, const int* in_sizes, int n_in,
                              void* d_out, int out_size, void* d_ws, size_t ws_size,
                              hipStream_t stream)
{
    const float* nodes = (const float*)d_in[0];
    const float* W1    = (const float*)d_in[1];
    const float* b1    = (const float*)d_in[2];
    const float* W2    = (const float*)d_in[3];
    const float* b2    = (const float*)d_in[4];
    const float* ea    = (const float*)d_in[5];
    float* out = (float*)d_out;

    unsigned short* w1t = (unsigned short*)d_ws;          // 8192 shorts
    unsigned short* w2t = w1t + 8192;                     // 4096 shorts
    float* attn = (float*)(w2t + 4096);                   // 9 floats

    prep_k<<<48, 256, 0, stream>>>(W1, W2, ea, w1t, w2t, attn);

    const int batches = (out_size / 64) / 3;              // 262144
    const int blocks = batches / (ITERS * 16);            // 2048
    edge_mfma5<<<blocks, 256, 0, stream>>>(nodes, w1t, w2t, attn, b1, b2, out);
}